// Round 12
// baseline (3879.663 us; speedup 1.0000x reference)
//
#include <hip/hip_runtime.h>
#include <hip/hip_bf16.h>

typedef __attribute__((ext_vector_type(8))) short short8;
typedef __attribute__((ext_vector_type(4))) float f32x4;
typedef __attribute__((ext_vector_type(4))) int i32x4;
typedef unsigned short u16;
typedef unsigned int u32;
typedef unsigned long long u64;

#define MFMA_BF16(a, b, c) __builtin_amdgcn_mfma_f32_16x16x32_bf16((a), (b), (c), 0, 0, 0)

// ---------------- workspace layout (bytes) ----------------
static constexpr size_t OFF_W   = 0;                       // 4 x [4096][1024] bf16 = 32MB
static constexpr size_t OFF_B0  = 33554432;                // 4096 f32 (bi0+bh0)
static constexpr size_t OFF_B1  = OFF_B0 + 16384;          // 4096 f32 (bi1+bh1)
static constexpr size_t OFF_H0  = OFF_B1 + 16384;          // 2 init h-slots (2 x 128KB, zeroed)
static constexpr size_t OFF_H1F = OFF_H0 + 262144;         // [32][1024] f32 (final h1)
static constexpr size_t OFF_XE  = OFF_H1F + 131072;        // [16384][1024] bf16 = 32MB
static constexpr size_t OFF_X0  = OFF_XE + 33554432;       // packed gates Xp = 128MB (also slot arena)
static constexpr size_t WS_NEED = OFF_X0 + 134217728;      // ~192.5 MB
// barrier counters: 32 x u32 at 128B stride (8KB region), overlaid on xe tail
static constexpr size_t OFF_FLG = OFF_X0 - 32768;

// Packed gate layout: Xp[t][blk][b][j][g] (u16), addr = t*131072 + blk*512 + b*16 + j*4 + g.
// h slot scheme (R7/R8, proven): slot(i) = {h0[t=i], h1[t=i-1]}, written at iter i via
// SYSTEM-bypass stores (MALL only), read at iter i+1 via NORMAL cached loads (XCD-L2
// amplifies). slot(-1)=hinit, slot(0)=hinit+64K u16, slot(i>=1) = Xp + (i-1)*131072.
// Every slot address is L2-allocated at most ONCE -> cached reads never stale.
// Barrier: group g = blk&31 (8 blocks each); block posts atomicAdd(cnt[g],1) after the
// drain barrier; all-arrived for step i+1  <=>  all 32 counters >= 8*(i+1). Counters
// are monotone (zeroed per call), so no reset races; poll is 32 lanes x 4B.

// ---------------- helpers ----------------
__device__ __forceinline__ u16 f2bf(float f) {
  u32 x = __builtin_bit_cast(u32, f);
  x += 0x7fffu + ((x >> 16) & 1u);   // RNE (inputs are finite)
  return (u16)(x >> 16);
}
__device__ __forceinline__ float bf2f(u16 u) {
  return __builtin_bit_cast(float, (u32)u << 16);
}
__device__ __forceinline__ float sigm(float x) { return 1.f / (1.f + expf(-x)); }

// system-scope (MALL-coherent) relaxed ops
__device__ __forceinline__ void sysstore64(void* p, u64 v) {
  __hip_atomic_store((u64*)p, v, __ATOMIC_RELAXED, __HIP_MEMORY_SCOPE_SYSTEM);
}
__device__ __forceinline__ u64 sysload64(const void* p) {
  return __hip_atomic_load((const u64*)p, __ATOMIC_RELAXED, __HIP_MEMORY_SCOPE_SYSTEM);
}

__device__ __forceinline__ void gload_lds16(const u16* gsrc, u16* ldst) {
  __builtin_amdgcn_global_load_lds(
      (__attribute__((address_space(1))) void*)(u16*)gsrc,
      (__attribute__((address_space(3))) void*)ldst, 16, 0, 0);
}

// ---------------- prep: fp32 weights -> bf16 ----------------
__global__ void prep_w_kernel(const float* __restrict__ Wi0, const float* __restrict__ Wh0,
                              const float* __restrict__ Wi1, const float* __restrict__ Wh1,
                              u16* __restrict__ dst) {
  size_t e = ((size_t)blockIdx.x * 256 + threadIdx.x) * 4;   // 16M elements total
  int mat = (int)(e >> 22);
  size_t off = e & ((1ull << 22) - 1);
  const float* src = (mat == 0) ? Wi0 : (mat == 1) ? Wh0 : (mat == 2) ? Wi1 : Wh1;
  float4 v = *(const float4*)(src + off);
  ushort4 o;
  o.x = f2bf(v.x); o.y = f2bf(v.y); o.z = f2bf(v.z); o.w = f2bf(v.w);
  *(ushort4*)(dst + e) = o;
}

__global__ void prep_b_kernel(const float* __restrict__ bi0, const float* __restrict__ bh0,
                              const float* __restrict__ bi1, const float* __restrict__ bh1,
                              float* __restrict__ b0, float* __restrict__ b1) {
  int i = blockIdx.x * 256 + threadIdx.x;   // 4096
  b0[i] = bi0[i] + bh0[i];
  b1[i] = bi1[i] + bh1[i];
}

// ---------------- embedding gather ----------------
__global__ void embed_kernel(const int* __restrict__ x, const float* __restrict__ emb,
                             u16* __restrict__ xe) {
  int m = blockIdx.x;            // m = t*32 + b
  int b = m & 31, t = m >> 5;
  int id = x[b * 512 + t];
  float4 v = ((const float4*)(emb + (size_t)id * 1024))[threadIdx.x];
  ushort4 o;
  o.x = f2bf(v.x); o.y = f2bf(v.y); o.z = f2bf(v.z); o.w = f2bf(v.w);
  *(ushort4*)(xe + (size_t)m * 1024 + threadIdx.x * 4) = o;
}

// ---------------- X0 GEMM -> block-packed gate layout Xp (+bias) ----------------
__global__ void x0_gemm_kernel(const u16* __restrict__ A, const u16* __restrict__ W,
                               const float* __restrict__ bias, u16* __restrict__ Xp) {
  __shared__ u16 lds[2][2][8192];   // [buf][A/B][128 rows x 64 cols]
  const int tid = threadIdx.x, l = tid & 63, w = tid >> 6;
  const int n0 = blockIdx.x * 128, m0 = blockIdx.y * 128;
  const int wm = w >> 1, wn = w & 1;
  const int row8 = l >> 3, u = l & 7;

  f32x4 acc[4][4];
#pragma unroll
  for (int a1 = 0; a1 < 4; ++a1)
#pragma unroll
    for (int a2 = 0; a2 < 4; ++a2) acc[a1][a2] = (f32x4){0.f, 0.f, 0.f, 0.f};

  auto stage = [&](int buf, int kt) {
    const int k0 = kt * 64;
#pragma unroll
    for (int q = 0; q < 4; ++q) {
      const int ld = w * 4 + q;
      const int row = ld * 8 + row8;
      const int sw = (u ^ (row & 7)) * 8;
      gload_lds16(A + (size_t)(m0 + row) * 1024 + k0 + sw, &lds[buf][0][ld * 512]);
      gload_lds16(W + (size_t)(n0 + row) * 1024 + k0 + sw, &lds[buf][1][ld * 512]);
    }
  };

  stage(0, 0);
  __syncthreads();

  for (int kt = 0; kt < 16; ++kt) {
    const int buf = kt & 1;
    if (kt < 15) stage(buf ^ 1, kt + 1);
    const u16* la = lds[buf][0];
    const u16* lb = lds[buf][1];
#pragma unroll
    for (int kk = 0; kk < 2; ++kk) {
      const int c = kk * 4 + (l >> 4);
      const int csw = (c ^ (l & 7)) * 8;    // row&7 == l&7 for all frag rows
      short8 af[4], bf[4];
#pragma unroll
      for (int mi = 0; mi < 4; ++mi) {
        int row = wm * 64 + mi * 16 + (l & 15);
        af[mi] = *(const short8*)(la + row * 64 + csw);
      }
#pragma unroll
      for (int ni = 0; ni < 4; ++ni) {
        int row = wn * 64 + ni * 16 + (l & 15);
        bf[ni] = *(const short8*)(lb + row * 64 + csw);
      }
#pragma unroll
      for (int mi = 0; mi < 4; ++mi)
#pragma unroll
        for (int ni = 0; ni < 4; ++ni)
          acc[mi][ni] = MFMA_BF16(af[mi], bf[ni], acc[mi][ni]);
    }
    __syncthreads();
  }

  // epilogue: packed write Xp[t][blkid][b][j][g]
#pragma unroll
  for (int ni = 0; ni < 4; ++ni) {
    int col = n0 + wn * 64 + ni * 16 + (l & 15);
    int g = col >> 10, blkid = (col & 1023) >> 2, j = col & 3;
    float bv = bias[col];
#pragma unroll
    for (int mi = 0; mi < 4; ++mi) {
#pragma unroll
      for (int r = 0; r < 4; ++r) {
        int row = m0 + wm * 64 + mi * 16 + (l >> 4) * 4 + r;
        int t = row >> 5, b = row & 31;
        Xp[(size_t)t * 131072 + blkid * 512 + b * 16 + j * 4 + g] =
            f2bf(acc[mi][ni][r] + bv);
      }
    }
  }
}

// ---------------- persistent recurrent kernel (R8 structure + counter barrier) ----------
// 256 blocks (1/CU), 256 threads (4 waves). Iter i = layer0(t=i) + layer1(t=i-1).
__launch_bounds__(256, 1)
__global__ void lstm_kernel(const u16* __restrict__ wbf, const float* __restrict__ b1v,
                            const u16* __restrict__ Xp, u16* __restrict__ hinit,
                            float* __restrict__ h1f, u32* __restrict__ cnt) {
  extern __shared__ char smem[];
  u16* wlds = (u16*)smem;                          // 3 * 16384 u16 = 98304 B
  float* gates0 = (float*)(smem + 98304);          // [32][16]  Wh0.h0
  float* part1  = (float*)(smem + 98304 + 2048);   // [32][16]  Wi1.h0
  float* wh1p   = (float*)(smem + 98304 + 4096);   // [32][16]  Wh1.h1

  const int tid = threadIdx.x;
  const int l = tid & 63, w = tid >> 6;
  const int blk = blockIdx.x;
  const int hbase = blk * 4;
  u16* Xw = (u16*)Xp;                              // slot writes into consumed gate slices

  // ---- fill weight LDS in MFMA fragment order
  for (int m = 0; m < 3; ++m) {
    const u16* Wm = wbf + (size_t)(m + 1) * (4096 * 1024);   // 1=Wh0, 2=Wi1, 3=Wh1
    for (int s = tid; s < 2048; s += 256) {
      int kk = s >> 6, ll = s & 63;
      int nl = ll & 15, hi = ll >> 4;
      int gr = (nl >> 2) * 1024 + hbase + (nl & 3);
      short8 v = *(const short8*)(Wm + (size_t)gr * 1024 + kk * 32 + hi * 8);
      *(short8*)(wlds + m * 16384 + kk * 512 + ll * 8) = v;
    }
  }
  __syncthreads();

  float cst = 0.f;                                 // threads 0..127: c0; 128..255: c1
  const int at = tid & 127, ab = at >> 2, aj = at & 3;
  const int mt = w & 1;

  float b1i = 0.f, b1fv = 0.f, b1g = 0.f, b1o = 0.f;
  if (tid >= 128) {
    b1i  = b1v[hbase + aj];
    b1fv = b1v[1024 + hbase + aj];
    b1g  = b1v[2048 + hbase + aj];
    b1o  = b1v[3072 + hbase + aj];
  }

  // gate chunk for step 0 (8B bypass; holds gates g=0..3 for this thread's (ab,aj))
  u64 gchunk = 0;
  if (tid < 128)
    gchunk = sysload64(Xp + blk * 512 + ab * 16 + aj * 4);

  const u32* cp = cnt + (size_t)(l & 31) * 32;     // poll: lanes 0..31 read one counter each

  for (int i = 0; i <= 512; ++i) {
    const u16* slot_r = (i == 0) ? hinit
                      : (i == 1) ? hinit + 65536
                                 : Xp + (size_t)(i - 2) * 131072;
    u16* slot_w = (i == 0) ? hinit + 65536
                           : Xw + (size_t)(i - 1) * 131072;

    asm volatile("" ::: "memory");   // pin loads below the previous barrier

    // ---- preload ALL h fragments: 32 x 16B NORMAL cached loads (L2-amplified broadcast)
    const u16* abase = slot_r + (w < 2 ? 0 : 32768)
                     + (mt * 16 + (l & 15)) * 1024 + ((l >> 4) * 8);
    short8 ar[32];
#pragma unroll
    for (int kk = 0; kk < 32; ++kk)
      ar[kk] = *(const short8*)(abase + kk * 32);

    if (w < 2) {   // waves 0,1: Wh0.h0 and Wi1.h0 (two independent chains each)
      f32x4 a0a = {0,0,0,0}, a0b = {0,0,0,0}, a1a = {0,0,0,0}, a1b = {0,0,0,0};
#pragma unroll
      for (int kk = 0; kk < 16; ++kk) {
        a0a = MFMA_BF16(ar[2 * kk],     *(const short8*)(wlds + (2 * kk) * 512 + l * 8), a0a);
        a1a = MFMA_BF16(ar[2 * kk],     *(const short8*)(wlds + 16384 + (2 * kk) * 512 + l * 8), a1a);
        a0b = MFMA_BF16(ar[2 * kk + 1], *(const short8*)(wlds + (2 * kk + 1) * 512 + l * 8), a0b);
        a1b = MFMA_BF16(ar[2 * kk + 1], *(const short8*)(wlds + 16384 + (2 * kk + 1) * 512 + l * 8), a1b);
      }
#pragma unroll
      for (int r = 0; r < 4; ++r) {
        int row = mt * 16 + (l >> 4) * 4 + r, col = l & 15;
        gates0[row * 16 + col] = a0a[r] + a0b[r];
        part1[row * 16 + col]  = a1a[r] + a1b[r];
      }
    } else {       // waves 2,3: Wh1.h1
      f32x4 a0a = {0,0,0,0}, a0b = {0,0,0,0};
#pragma unroll
      for (int kk = 0; kk < 16; ++kk) {
        a0a = MFMA_BF16(ar[2 * kk],     *(const short8*)(wlds + 2 * 16384 + (2 * kk) * 512 + l * 8), a0a);
        a0b = MFMA_BF16(ar[2 * kk + 1], *(const short8*)(wlds + 2 * 16384 + (2 * kk + 1) * 512 + l * 8), a0b);
      }
#pragma unroll
      for (int r = 0; r < 4; ++r) {
        int row = mt * 16 + (l >> 4) * 4 + r, col = l & 15;
        wh1p[row * 16 + col] = a0a[r] + a0b[r];
      }
    }
    __syncthreads();

    // ---- activations + h slot store (packed 8B system store per 4 dims)
    if (tid < 128) {
      if (i < 512) {
        float gi = gates0[ab * 16 + aj]      + bf2f((u16)(gchunk));
        float gf = gates0[ab * 16 + 4 + aj]  + bf2f((u16)(gchunk >> 16));
        float gg = gates0[ab * 16 + 8 + aj]  + bf2f((u16)(gchunk >> 32));
        float go = gates0[ab * 16 + 12 + aj] + bf2f((u16)(gchunk >> 48));
        cst = sigm(gf) * cst + sigm(gi) * tanhf(gg);
        float h = sigm(go) * tanhf(cst);
        u32 hv = (u32)f2bf(h);
        u32 p1 = (u32)__shfl_xor((int)hv, 1);
        u32 lo = (aj & 1) ? ((p1 & 0xffff) | (hv << 16)) : ((hv & 0xffff) | (p1 << 16));
        u32 p2 = (u32)__shfl_xor((int)lo, 2);
        if (aj == 0)
          sysstore64(slot_w + ab * 1024 + hbase, (u64)lo | ((u64)p2 << 32));
      }
    } else {
      if (i >= 1) {
        float gi = part1[ab * 16 + aj]      + wh1p[ab * 16 + aj]      + b1i;
        float gf = part1[ab * 16 + 4 + aj]  + wh1p[ab * 16 + 4 + aj]  + b1fv;
        float gg = part1[ab * 16 + 8 + aj]  + wh1p[ab * 16 + 8 + aj]  + b1g;
        float go = part1[ab * 16 + 12 + aj] + wh1p[ab * 16 + 12 + aj] + b1o;
        cst = sigm(gf) * cst + sigm(gi) * tanhf(gg);
        float h = sigm(go) * tanhf(cst);
        u32 hv = (u32)f2bf(h);
        u32 p1 = (u32)__shfl_xor((int)hv, 1);
        u32 lo = (aj & 1) ? ((p1 & 0xffff) | (hv << 16)) : ((hv & 0xffff) | (p1 << 16));
        u32 p2 = (u32)__shfl_xor((int)lo, 2);
        if (aj == 0)
          sysstore64(slot_w + 32768 + ab * 1024 + hbase, (u64)lo | ((u64)p2 << 32));
        if (i == 512) h1f[ab * 1024 + hbase + aj] = h;
      }
    }

    if (i == 512) break;                 // done; no final barrier needed

    // ---- counter barrier: post one atomicAdd, prefetch gates, 32-lane poll
    __syncthreads();                     // all h system-stores drained (vmcnt 0, all waves)
    const u32 target = (u32)(i + 1);
    if (tid == 0)
      __hip_atomic_fetch_add(&cnt[(size_t)(blk & 31) * 32], 1u,
                             __ATOMIC_RELAXED, __HIP_MEMORY_SCOPE_SYSTEM);

    // prefetch next step's gate chunk under the barrier wait
    if (tid < 128 && i + 1 < 512)
      gchunk = sysload64(Xp + (size_t)(i + 1) * 131072 + blk * 512 + ab * 16 + aj * 4);

    if (w == 0) {                        // lanes 0..31 each watch one counter (4B)
      const u32 tgt8 = 8u * target;
      u32 c = 0xFFFFFFFFu;
      while (true) {
        if (l < 32) {
          asm volatile("global_load_dword %0, %1, off sc0 sc1"
                       : "=&v"(c) : "v"(cp));
          asm volatile("s_waitcnt vmcnt(0)" ::: "memory");
        }
        if (__all(c >= tgt8)) break;
      }
    }
    __syncthreads();                     // whole block proceeds once wave 0 confirms
  }
}

// ---------------- final FC: fcw read exactly once; h1 staged in LDS ----------------
__global__ void __launch_bounds__(512) fc_kernel(const float* __restrict__ h1f,
                                                 const float* __restrict__ fcw,
                                                 const float* __restrict__ fcb,
                                                 float* __restrict__ out) {
  extern __shared__ float hls[];                  // [32][1024] fp32 = 128KB
  for (int s = threadIdx.x; s < 8192; s += 512)
    ((float4*)hls)[s] = ((const float4*)h1f)[s];
  __syncthreads();
  const int w = threadIdx.x >> 6, l = threadIdx.x & 63;
  const int vbase = blockIdx.x * 128 + w * 16;    // grid 250 x 8 waves x 16 v = 32000
  for (int vi = 0; vi < 16; ++vi) {
    const int v = vbase + vi;
    const float4* wr = (const float4*)(fcw + (size_t)v * 1024);
    float4 f0 = wr[l], f1 = wr[64 + l], f2 = wr[128 + l], f3 = wr[192 + l];
    float bias = fcb[v];
    for (int b = 0; b < 32; ++b) {
      const float4* hb = (const float4*)(hls + b * 1024);
      float4 h0 = hb[l], h1 = hb[64 + l], h2 = hb[128 + l], h3 = hb[192 + l];
      float s = f0.x*h0.x + f0.y*h0.y + f0.z*h0.z + f0.w*h0.w
              + f1.x*h1.x + f1.y*h1.y + f1.z*h1.z + f1.w*h1.w
              + f2.x*h2.x + f2.y*h2.y + f2.z*h2.z + f2.w*h2.w
              + f3.x*h3.x + f3.y*h3.y + f3.z*h3.z + f3.w*h3.w;
      s += __shfl_xor(s, 1);  s += __shfl_xor(s, 2);  s += __shfl_xor(s, 4);
      s += __shfl_xor(s, 8);  s += __shfl_xor(s, 16); s += __shfl_xor(s, 32);
      if (l == 0) out[(size_t)b * 32000 + v] = s + bias;
    }
  }
}

// ---------------- host launch ----------------
extern "C" void kernel_launch(void* const* d_in, const int* in_sizes, int n_in,
                              void* d_out, int out_size, void* d_ws, size_t ws_size,
                              hipStream_t stream) {
  const int*   x   = (const int*)d_in[0];
  const float* emb = (const float*)d_in[1];
  const float* Wi0 = (const float*)d_in[2];
  const float* bi0 = (const float*)d_in[3];
  const float* Wh0 = (const float*)d_in[4];
  const float* bh0 = (const float*)d_in[5];
  const float* Wi1 = (const float*)d_in[6];
  const float* bi1 = (const float*)d_in[7];
  const float* Wh1 = (const float*)d_in[8];
  const float* bh1 = (const float*)d_in[9];
  const float* fcw = (const float*)d_in[10];
  const float* fcb = (const float*)d_in[11];
  float* out = (float*)d_out;
  char* ws = (char*)d_ws;

  if (ws_size < WS_NEED) return;

  u16*   wbf = (u16*)(ws + OFF_W);
  float* b0v = (float*)(ws + OFF_B0);
  float* b1v = (float*)(ws + OFF_B1);
  u16*   hin = (u16*)(ws + OFF_H0);
  float* h1f = (float*)(ws + OFF_H1F);
  u16*   xe  = (u16*)(ws + OFF_XE);
  u16*   Xp  = (u16*)(ws + OFF_X0);
  u32*   cnt = (u32*)(ws + OFF_FLG);

  // zero init slots + h1f every call (replays must be identical)
  hipMemsetAsync(ws + OFF_H0, 0, OFF_XE - OFF_H0, stream);

  prep_w_kernel<<<16384, 256, 0, stream>>>(Wi0, Wh0, Wi1, Wh1, wbf);
  prep_b_kernel<<<16, 256, 0, stream>>>(bi0, bh0, bi1, bh1, b0v, b1v);
  embed_kernel<<<16384, 256, 0, stream>>>(x, emb, xe);
  x0_gemm_kernel<<<dim3(32, 128), 256, 0, stream>>>(xe, wbf, b0v, Xp);

  // xe tail is dead now -> barrier counters (zeroed per call; monotone within a call)
  hipMemsetAsync(ws + OFF_FLG, 0, 8192, stream);

  hipFuncSetAttribute((const void*)lstm_kernel,
                      hipFuncAttributeMaxDynamicSharedMemorySize, 104448);
  lstm_kernel<<<256, 256, 104448, stream>>>(wbf, b1v, Xp, hin, h1f, cnt);

  hipFuncSetAttribute((const void*)fc_kernel,
                      hipFuncAttributeMaxDynamicSharedMemorySize, 131072);
  fc_kernel<<<250, 512, 131072, stream>>>(h1f, fcw, fcb, out);
}

// Round 13
// 3438.590 us; speedup vs baseline: 1.1283x; 1.1283x over previous
//
#include <hip/hip_runtime.h>
#include <hip/hip_bf16.h>

typedef __attribute__((ext_vector_type(8))) short short8;
typedef __attribute__((ext_vector_type(4))) float f32x4;
typedef __attribute__((ext_vector_type(4))) int i32x4;
typedef unsigned short u16;
typedef unsigned int u32;
typedef unsigned long long u64;

#define MFMA_BF16(a, b, c) __builtin_amdgcn_mfma_f32_16x16x32_bf16((a), (b), (c), 0, 0, 0)

// ---------------- workspace layout (bytes) ----------------
static constexpr size_t OFF_W   = 0;                       // 4 x [4096][1024] bf16 = 32MB
static constexpr size_t OFF_B0  = 33554432;                // 4096 f32 (bi0+bh0)
static constexpr size_t OFF_B1  = OFF_B0 + 16384;          // 4096 f32 (bi1+bh1)
static constexpr size_t OFF_H0  = OFF_B1 + 16384;          // 2 init h-slots (2 x 128KB, zeroed)
static constexpr size_t OFF_H1F = OFF_H0 + 262144;         // [32][1024] f32 (final h1)
static constexpr size_t OFF_XE  = OFF_H1F + 131072;        // [16384][1024] bf16 = 32MB
static constexpr size_t OFF_X0  = OFF_XE + 33554432;       // packed gates Xp = 128MB (also slot arena)
static constexpr size_t WS_NEED = OFF_X0 + 134217728;      // ~192.5 MB
// dense barrier flags: 256 x u32 (1KB), overlaid on xe tail (dead after x0_gemm)
static constexpr size_t OFF_FLG = OFF_X0 - 4096;

// Packed gate layout: Xp[t][blk][b][j][g] (u16), addr = t*131072 + blk*512 + b*16 + j*4 + g.
// h slot scheme (R7/R8, proven): slot(i) = {h0[t=i], h1[t=i-1]}, written at iter i via
// SYSTEM-bypass stores (MALL only), read at iter i+1 via NORMAL cached loads (XCD-L2
// amplifies). slot(-1)=hinit, slot(0)=hinit+64K u16, slot(i>=1) = Xp + (i-1)*131072.
// Every slot address is L2-allocated at most ONCE -> cached reads never stale.
// Barrier (R8/R11, proven): writer posts 4B system store to flagsD[blk]; wave 0 polls
// all 256 flags with one 16B bypass load per lane. Structural note (R9/R10/R12
// post-mortems): both h0->h0 and h1->h1 recurrences need their full
// store->flag->read round-trip inside ONE barrier interval; this lockstep
// one-post/one-poll structure is the proven optimum of the sync-topology family.

// ---------------- helpers ----------------
__device__ __forceinline__ u16 f2bf(float f) {
  u32 x = __builtin_bit_cast(u32, f);
  x += 0x7fffu + ((x >> 16) & 1u);   // RNE (inputs are finite)
  return (u16)(x >> 16);
}
__device__ __forceinline__ float bf2f(u16 u) {
  return __builtin_bit_cast(float, (u32)u << 16);
}

// fast transcendentals on the critical path: v_exp_f32 (2^x) + v_rcp_f32, ~1ulp
__device__ __forceinline__ float fexp2(float x) {
  float r; asm("v_exp_f32 %0, %1" : "=v"(r) : "v"(x)); return r;
}
__device__ __forceinline__ float frcp(float x) {
  float r; asm("v_rcp_f32 %0, %1" : "=v"(r) : "v"(x)); return r;
}
__device__ __forceinline__ float sigm(float x) {
  // 1/(1+e^-x); e^-x = 2^(-x*log2e). Large |x| saturates cleanly (inf -> 0, 0 -> 1).
  return frcp(1.f + fexp2(-1.44269504f * x));
}
__device__ __forceinline__ float ftanh(float x) {
  // tanh = (e^2x - 1)/(e^2x + 1); clamp to +-15 to avoid inf/inf (c-state unbounded).
  float xc = fminf(fmaxf(x, -15.f), 15.f);
  float e = fexp2(2.88539008f * xc);
  return (e - 1.f) * frcp(e + 1.f);
}

// system-scope (MALL-coherent) relaxed ops
__device__ __forceinline__ void sysstore64(void* p, u64 v) {
  __hip_atomic_store((u64*)p, v, __ATOMIC_RELAXED, __HIP_MEMORY_SCOPE_SYSTEM);
}
__device__ __forceinline__ u64 sysload64(const void* p) {
  return __hip_atomic_load((const u64*)p, __ATOMIC_RELAXED, __HIP_MEMORY_SCOPE_SYSTEM);
}

__device__ __forceinline__ void gload_lds16(const u16* gsrc, u16* ldst) {
  __builtin_amdgcn_global_load_lds(
      (__attribute__((address_space(1))) void*)(u16*)gsrc,
      (__attribute__((address_space(3))) void*)ldst, 16, 0, 0);
}

// ---------------- prep: fp32 weights -> bf16 ----------------
__global__ void prep_w_kernel(const float* __restrict__ Wi0, const float* __restrict__ Wh0,
                              const float* __restrict__ Wi1, const float* __restrict__ Wh1,
                              u16* __restrict__ dst) {
  size_t e = ((size_t)blockIdx.x * 256 + threadIdx.x) * 4;   // 16M elements total
  int mat = (int)(e >> 22);
  size_t off = e & ((1ull << 22) - 1);
  const float* src = (mat == 0) ? Wi0 : (mat == 1) ? Wh0 : (mat == 2) ? Wi1 : Wh1;
  float4 v = *(const float4*)(src + off);
  ushort4 o;
  o.x = f2bf(v.x); o.y = f2bf(v.y); o.z = f2bf(v.z); o.w = f2bf(v.w);
  *(ushort4*)(dst + e) = o;
}

__global__ void prep_b_kernel(const float* __restrict__ bi0, const float* __restrict__ bh0,
                              const float* __restrict__ bi1, const float* __restrict__ bh1,
                              float* __restrict__ b0, float* __restrict__ b1) {
  int i = blockIdx.x * 256 + threadIdx.x;   // 4096
  b0[i] = bi0[i] + bh0[i];
  b1[i] = bi1[i] + bh1[i];
}

// ---------------- embedding gather ----------------
__global__ void embed_kernel(const int* __restrict__ x, const float* __restrict__ emb,
                             u16* __restrict__ xe) {
  int m = blockIdx.x;            // m = t*32 + b
  int b = m & 31, t = m >> 5;
  int id = x[b * 512 + t];
  float4 v = ((const float4*)(emb + (size_t)id * 1024))[threadIdx.x];
  ushort4 o;
  o.x = f2bf(v.x); o.y = f2bf(v.y); o.z = f2bf(v.z); o.w = f2bf(v.w);
  *(ushort4*)(xe + (size_t)m * 1024 + threadIdx.x * 4) = o;
}

// ---------------- X0 GEMM -> block-packed gate layout Xp (+bias) ----------------
__global__ void x0_gemm_kernel(const u16* __restrict__ A, const u16* __restrict__ W,
                               const float* __restrict__ bias, u16* __restrict__ Xp) {
  __shared__ u16 lds[2][2][8192];   // [buf][A/B][128 rows x 64 cols]
  const int tid = threadIdx.x, l = tid & 63, w = tid >> 6;
  const int n0 = blockIdx.x * 128, m0 = blockIdx.y * 128;
  const int wm = w >> 1, wn = w & 1;
  const int row8 = l >> 3, u = l & 7;

  f32x4 acc[4][4];
#pragma unroll
  for (int a1 = 0; a1 < 4; ++a1)
#pragma unroll
    for (int a2 = 0; a2 < 4; ++a2) acc[a1][a2] = (f32x4){0.f, 0.f, 0.f, 0.f};

  auto stage = [&](int buf, int kt) {
    const int k0 = kt * 64;
#pragma unroll
    for (int q = 0; q < 4; ++q) {
      const int ld = w * 4 + q;
      const int row = ld * 8 + row8;
      const int sw = (u ^ (row & 7)) * 8;
      gload_lds16(A + (size_t)(m0 + row) * 1024 + k0 + sw, &lds[buf][0][ld * 512]);
      gload_lds16(W + (size_t)(n0 + row) * 1024 + k0 + sw, &lds[buf][1][ld * 512]);
    }
  };

  stage(0, 0);
  __syncthreads();

  for (int kt = 0; kt < 16; ++kt) {
    const int buf = kt & 1;
    if (kt < 15) stage(buf ^ 1, kt + 1);
    const u16* la = lds[buf][0];
    const u16* lb = lds[buf][1];
#pragma unroll
    for (int kk = 0; kk < 2; ++kk) {
      const int c = kk * 4 + (l >> 4);
      const int csw = (c ^ (l & 7)) * 8;    // row&7 == l&7 for all frag rows
      short8 af[4], bf[4];
#pragma unroll
      for (int mi = 0; mi < 4; ++mi) {
        int row = wm * 64 + mi * 16 + (l & 15);
        af[mi] = *(const short8*)(la + row * 64 + csw);
      }
#pragma unroll
      for (int ni = 0; ni < 4; ++ni) {
        int row = wn * 64 + ni * 16 + (l & 15);
        bf[ni] = *(const short8*)(lb + row * 64 + csw);
      }
#pragma unroll
      for (int mi = 0; mi < 4; ++mi)
#pragma unroll
        for (int ni = 0; ni < 4; ++ni)
          acc[mi][ni] = MFMA_BF16(af[mi], bf[ni], acc[mi][ni]);
    }
    __syncthreads();
  }

  // epilogue: packed write Xp[t][blkid][b][j][g]
#pragma unroll
  for (int ni = 0; ni < 4; ++ni) {
    int col = n0 + wn * 64 + ni * 16 + (l & 15);
    int g = col >> 10, blkid = (col & 1023) >> 2, j = col & 3;
    float bv = bias[col];
#pragma unroll
    for (int mi = 0; mi < 4; ++mi) {
#pragma unroll
      for (int r = 0; r < 4; ++r) {
        int row = m0 + wm * 64 + mi * 16 + (l >> 4) * 4 + r;
        int t = row >> 5, b = row & 31;
        Xp[(size_t)t * 131072 + blkid * 512 + b * 16 + j * 4 + g] =
            f2bf(acc[mi][ni][r] + bv);
      }
    }
  }
}

// ---------------- persistent recurrent kernel (R8/R11 structure, proven) ----------------
// 256 blocks (1/CU), 256 threads (4 waves). Iter i = layer0(t=i) + layer1(t=i-1).
__launch_bounds__(256, 1)
__global__ void lstm_kernel(const u16* __restrict__ wbf, const float* __restrict__ b1v,
                            const u16* __restrict__ Xp, u16* __restrict__ hinit,
                            float* __restrict__ h1f, u32* __restrict__ flagsD) {
  extern __shared__ char smem[];
  u16* wlds = (u16*)smem;                          // 3 * 16384 u16 = 98304 B
  float* gates0 = (float*)(smem + 98304);          // [32][16]  Wh0.h0
  float* part1  = (float*)(smem + 98304 + 2048);   // [32][16]  Wi1.h0
  float* wh1p   = (float*)(smem + 98304 + 4096);   // [32][16]  Wh1.h1

  const int tid = threadIdx.x;
  const int l = tid & 63, w = tid >> 6;
  const int blk = blockIdx.x;
  const int hbase = blk * 4;
  u16* Xw = (u16*)Xp;                              // slot writes into consumed gate slices

  // ---- fill weight LDS in MFMA fragment order
  for (int m = 0; m < 3; ++m) {
    const u16* Wm = wbf + (size_t)(m + 1) * (4096 * 1024);   // 1=Wh0, 2=Wi1, 3=Wh1
    for (int s = tid; s < 2048; s += 256) {
      int kk = s >> 6, ll = s & 63;
      int nl = ll & 15, hi = ll >> 4;
      int gr = (nl >> 2) * 1024 + hbase + (nl & 3);
      short8 v = *(const short8*)(Wm + (size_t)gr * 1024 + kk * 32 + hi * 8);
      *(short8*)(wlds + m * 16384 + kk * 512 + ll * 8) = v;
    }
  }
  __syncthreads();

  float cst = 0.f;                                 // threads 0..127: c0; 128..255: c1
  const int at = tid & 127, ab = at >> 2, aj = at & 3;
  const int mt = w & 1;

  float b1i = 0.f, b1fv = 0.f, b1g = 0.f, b1o = 0.f;
  if (tid >= 128) {
    b1i  = b1v[hbase + aj];
    b1fv = b1v[1024 + hbase + aj];
    b1g  = b1v[2048 + hbase + aj];
    b1o  = b1v[3072 + hbase + aj];
  }

  // gate chunk for step 0 (8B bypass; holds gates g=0..3 for this thread's (ab,aj))
  u64 gchunk = 0;
  if (tid < 128)
    gchunk = sysload64(Xp + blk * 512 + ab * 16 + aj * 4);

  const u32* fquad = flagsD + l * 4;               // wave-0 poll: 4 flags per lane

  for (int i = 0; i <= 512; ++i) {
    const u16* slot_r = (i == 0) ? hinit
                      : (i == 1) ? hinit + 65536
                                 : Xp + (size_t)(i - 2) * 131072;
    u16* slot_w = (i == 0) ? hinit + 65536
                           : Xw + (size_t)(i - 1) * 131072;

    asm volatile("" ::: "memory");   // pin loads below the previous barrier

    // ---- preload ALL h fragments: 32 x 16B NORMAL cached loads (L2-amplified broadcast)
    const u16* abase = slot_r + (w < 2 ? 0 : 32768)
                     + (mt * 16 + (l & 15)) * 1024 + ((l >> 4) * 8);
    short8 ar[32];
#pragma unroll
    for (int kk = 0; kk < 32; ++kk)
      ar[kk] = *(const short8*)(abase + kk * 32);

    if (w < 2) {   // waves 0,1: Wh0.h0 and Wi1.h0 (two independent chains each)
      f32x4 a0a = {0,0,0,0}, a0b = {0,0,0,0}, a1a = {0,0,0,0}, a1b = {0,0,0,0};
#pragma unroll
      for (int kk = 0; kk < 16; ++kk) {
        a0a = MFMA_BF16(ar[2 * kk],     *(const short8*)(wlds + (2 * kk) * 512 + l * 8), a0a);
        a1a = MFMA_BF16(ar[2 * kk],     *(const short8*)(wlds + 16384 + (2 * kk) * 512 + l * 8), a1a);
        a0b = MFMA_BF16(ar[2 * kk + 1], *(const short8*)(wlds + (2 * kk + 1) * 512 + l * 8), a0b);
        a1b = MFMA_BF16(ar[2 * kk + 1], *(const short8*)(wlds + 16384 + (2 * kk + 1) * 512 + l * 8), a1b);
      }
#pragma unroll
      for (int r = 0; r < 4; ++r) {
        int row = mt * 16 + (l >> 4) * 4 + r, col = l & 15;
        gates0[row * 16 + col] = a0a[r] + a0b[r];
        part1[row * 16 + col]  = a1a[r] + a1b[r];
      }
    } else {       // waves 2,3: Wh1.h1
      f32x4 a0a = {0,0,0,0}, a0b = {0,0,0,0};
#pragma unroll
      for (int kk = 0; kk < 16; ++kk) {
        a0a = MFMA_BF16(ar[2 * kk],     *(const short8*)(wlds + 2 * 16384 + (2 * kk) * 512 + l * 8), a0a);
        a0b = MFMA_BF16(ar[2 * kk + 1], *(const short8*)(wlds + 2 * 16384 + (2 * kk + 1) * 512 + l * 8), a0b);
      }
#pragma unroll
      for (int r = 0; r < 4; ++r) {
        int row = mt * 16 + (l >> 4) * 4 + r, col = l & 15;
        wh1p[row * 16 + col] = a0a[r] + a0b[r];
      }
    }
    __syncthreads();

    // ---- activations + h slot store (packed 8B system store per 4 dims)
    if (tid < 128) {
      if (i < 512) {
        float gi = gates0[ab * 16 + aj]      + bf2f((u16)(gchunk));
        float gf = gates0[ab * 16 + 4 + aj]  + bf2f((u16)(gchunk >> 16));
        float gg = gates0[ab * 16 + 8 + aj]  + bf2f((u16)(gchunk >> 32));
        float go = gates0[ab * 16 + 12 + aj] + bf2f((u16)(gchunk >> 48));
        cst = sigm(gf) * cst + sigm(gi) * ftanh(gg);
        float h = sigm(go) * ftanh(cst);
        u32 hv = (u32)f2bf(h);
        u32 p1 = (u32)__shfl_xor((int)hv, 1);
        u32 lo = (aj & 1) ? ((p1 & 0xffff) | (hv << 16)) : ((hv & 0xffff) | (p1 << 16));
        u32 p2 = (u32)__shfl_xor((int)lo, 2);
        if (aj == 0)
          sysstore64(slot_w + ab * 1024 + hbase, (u64)lo | ((u64)p2 << 32));
      }
    } else {
      if (i >= 1) {
        float gi = part1[ab * 16 + aj]      + wh1p[ab * 16 + aj]      + b1i;
        float gf = part1[ab * 16 + 4 + aj]  + wh1p[ab * 16 + 4 + aj]  + b1fv;
        float gg = part1[ab * 16 + 8 + aj]  + wh1p[ab * 16 + 8 + aj]  + b1g;
        float go = part1[ab * 16 + 12 + aj] + wh1p[ab * 16 + 12 + aj] + b1o;
        cst = sigm(gf) * cst + sigm(gi) * ftanh(gg);
        float h = sigm(go) * ftanh(cst);
        u32 hv = (u32)f2bf(h);
        u32 p1 = (u32)__shfl_xor((int)hv, 1);
        u32 lo = (aj & 1) ? ((p1 & 0xffff) | (hv << 16)) : ((hv & 0xffff) | (p1 << 16));
        u32 p2 = (u32)__shfl_xor((int)lo, 2);
        if (aj == 0)
          sysstore64(slot_w + 32768 + ab * 1024 + hbase, (u64)lo | ((u64)p2 << 32));
        if (i == 512) h1f[ab * 1024 + hbase + aj] = h;
      }
    }

    if (i == 512) break;                 // done; no final barrier needed

    // ---- dense-flag barrier: post, prefetch gates, wave-0 poll
    __syncthreads();                     // all h system-stores drained (vmcnt 0, all waves)
    const u32 target = (u32)(i + 1);
    if (tid == 0)
      __hip_atomic_store(&flagsD[blk], target, __ATOMIC_RELAXED, __HIP_MEMORY_SCOPE_SYSTEM);

    // prefetch next step's gate chunk under the barrier wait
    if (tid < 128 && i + 1 < 512)
      gchunk = sysload64(Xp + (size_t)(i + 1) * 131072 + blk * 512 + ab * 16 + aj * 4);

    if (w == 0) {                        // 64 lanes x 4 flags = all 256, one 16B load/lane
      while (true) {
        i32x4 v;
        asm volatile("global_load_dwordx4 %0, %1, off sc0 sc1"
                     : "=&v"(v) : "v"(fquad));
        asm volatile("s_waitcnt vmcnt(0)" ::: "memory");
        u32 m01 = min((u32)v.x, (u32)v.y);
        u32 m23 = min((u32)v.z, (u32)v.w);
        if (__all(min(m01, m23) >= target)) break;
      }
    }
    __syncthreads();                     // whole block proceeds once wave 0 confirms
  }
}

// ---------------- final FC: fcw read exactly once; h1 staged in LDS ----------------
__global__ void __launch_bounds__(512) fc_kernel(const float* __restrict__ h1f,
                                                 const float* __restrict__ fcw,
                                                 const float* __restrict__ fcb,
                                                 float* __restrict__ out) {
  extern __shared__ float hls[];                  // [32][1024] fp32 = 128KB
  for (int s = threadIdx.x; s < 8192; s += 512)
    ((float4*)hls)[s] = ((const float4*)h1f)[s];
  __syncthreads();
  const int w = threadIdx.x >> 6, l = threadIdx.x & 63;
  const int vbase = blockIdx.x * 128 + w * 16;    // grid 250 x 8 waves x 16 v = 32000
  for (int vi = 0; vi < 16; ++vi) {
    const int v = vbase + vi;
    const float4* wr = (const float4*)(fcw + (size_t)v * 1024);
    float4 f0 = wr[l], f1 = wr[64 + l], f2 = wr[128 + l], f3 = wr[192 + l];
    float bias = fcb[v];
    for (int b = 0; b < 32; ++b) {
      const float4* hb = (const float4*)(hls + b * 1024);
      float4 h0 = hb[l], h1 = hb[64 + l], h2 = hb[128 + l], h3 = hb[192 + l];
      float s = f0.x*h0.x + f0.y*h0.y + f0.z*h0.z + f0.w*h0.w
              + f1.x*h1.x + f1.y*h1.y + f1.z*h1.z + f1.w*h1.w
              + f2.x*h2.x + f2.y*h2.y + f2.z*h2.z + f2.w*h2.w
              + f3.x*h3.x + f3.y*h3.y + f3.z*h3.z + f3.w*h3.w;
      s += __shfl_xor(s, 1);  s += __shfl_xor(s, 2);  s += __shfl_xor(s, 4);
      s += __shfl_xor(s, 8);  s += __shfl_xor(s, 16); s += __shfl_xor(s, 32);
      if (l == 0) out[(size_t)b * 32000 + v] = s + bias;
    }
  }
}

// ---------------- host launch ----------------
extern "C" void kernel_launch(void* const* d_in, const int* in_sizes, int n_in,
                              void* d_out, int out_size, void* d_ws, size_t ws_size,
                              hipStream_t stream) {
  const int*   x   = (const int*)d_in[0];
  const float* emb = (const float*)d_in[1];
  const float* Wi0 = (const float*)d_in[2];
  const float* bi0 = (const float*)d_in[3];
  const float* Wh0 = (const float*)d_in[4];
  const float* bh0 = (const float*)d_in[5];
  const float* Wi1 = (const float*)d_in[6];
  const float* bi1 = (const float*)d_in[7];
  const float* Wh1 = (const float*)d_in[8];
  const float* bh1 = (const float*)d_in[9];
  const float* fcw = (const float*)d_in[10];
  const float* fcb = (const float*)d_in[11];
  float* out = (float*)d_out;
  char* ws = (char*)d_ws;

  if (ws_size < WS_NEED) return;

  u16*   wbf = (u16*)(ws + OFF_W);
  float* b0v = (float*)(ws + OFF_B0);
  float* b1v = (float*)(ws + OFF_B1);
  u16*   hin = (u16*)(ws + OFF_H0);
  float* h1f = (float*)(ws + OFF_H1F);
  u16*   xe  = (u16*)(ws + OFF_XE);
  u16*   Xp  = (u16*)(ws + OFF_X0);
  u32*   flg = (u32*)(ws + OFF_FLG);

  // zero init slots + h1f every call (replays must be identical)
  hipMemsetAsync(ws + OFF_H0, 0, OFF_XE - OFF_H0, stream);

  prep_w_kernel<<<16384, 256, 0, stream>>>(Wi0, Wh0, Wi1, Wh1, wbf);
  prep_b_kernel<<<16, 256, 0, stream>>>(bi0, bh0, bi1, bh1, b0v, b1v);
  embed_kernel<<<16384, 256, 0, stream>>>(x, emb, xe);
  x0_gemm_kernel<<<dim3(32, 128), 256, 0, stream>>>(xe, wbf, b0v, Xp);

  // xe tail is dead now -> dense barrier flags (zeroed per call)
  hipMemsetAsync(ws + OFF_FLG, 0, 4096, stream);

  hipFuncSetAttribute((const void*)lstm_kernel,
                      hipFuncAttributeMaxDynamicSharedMemorySize, 104448);
  lstm_kernel<<<256, 256, 104448, stream>>>(wbf, b1v, Xp, hin, h1f, flg);

  hipFuncSetAttribute((const void*)fc_kernel,
                      hipFuncAttributeMaxDynamicSharedMemorySize, 131072);
  fc_kernel<<<250, 512, 131072, stream>>>(h1f, fcw, fcb, out);
}

// Round 14
// 3428.179 us; speedup vs baseline: 1.1317x; 1.0030x over previous
//
#include <hip/hip_runtime.h>
#include <hip/hip_bf16.h>

typedef __attribute__((ext_vector_type(8))) short short8;
typedef __attribute__((ext_vector_type(4))) float f32x4;
typedef __attribute__((ext_vector_type(4))) int i32x4;
typedef unsigned short u16;
typedef unsigned int u32;
typedef unsigned long long u64;

#define MFMA_BF16(a, b, c) __builtin_amdgcn_mfma_f32_16x16x32_bf16((a), (b), (c), 0, 0, 0)

// ---------------- workspace layout (bytes) ----------------
static constexpr size_t OFF_W   = 0;                       // 4 x [4096][1024] bf16 = 32MB
static constexpr size_t OFF_B0  = 33554432;                // 4096 f32 (bi0+bh0)
static constexpr size_t OFF_B1  = OFF_B0 + 16384;          // 4096 f32 (bi1+bh1)
static constexpr size_t OFF_H0  = OFF_B1 + 16384;          // 2 init h-slots (2 x 128KB, zeroed)
static constexpr size_t OFF_H1F = OFF_H0 + 262144;         // [32][1024] f32 (final h1)
static constexpr size_t OFF_XE  = OFF_H1F + 131072;        // [16384][1024] bf16 = 32MB
static constexpr size_t OFF_X0  = OFF_XE + 33554432;       // packed gates Xp = 128MB (also slot arena)
static constexpr size_t WS_NEED = OFF_X0 + 134217728;      // ~192.5 MB
// dense barrier flags: 256 x u32 (1KB), overlaid on xe tail (dead after x0_gemm)
static constexpr size_t OFF_FLG = OFF_X0 - 4096;

// Packed gate layout: Xp[t][blk][b][j][g] (u16), addr = t*131072 + blk*512 + b*16 + j*4 + g.
// h slot scheme (R7/R8, proven): slot(i) = {h0[t=i], h1[t=i-1]}, written at iter i via
// SYSTEM-bypass stores (MALL only), read at iter i+1 via NORMAL cached loads (XCD-L2
// amplifies). slot(-1)=hinit, slot(0)=hinit+64K u16, slot(i>=1) = Xp + (i-1)*131072.
// Every slot address is L2-allocated at most ONCE -> cached reads never stale.
// Barrier (R8/R11, proven): writer posts 4B system store to flagsD[blk]; wave 0 polls
// all 256 flags with one 16B bypass load per lane. Lockstep one-post/one-poll is the
// proven optimum of the sync-topology family (R9/R10/R12 post-mortems).

// ---------------- helpers ----------------
__device__ __forceinline__ u16 f2bf(float f) {
  u32 x = __builtin_bit_cast(u32, f);
  x += 0x7fffu + ((x >> 16) & 1u);   // RNE (inputs are finite)
  return (u16)(x >> 16);
}
__device__ __forceinline__ float bf2f(u16 u) {
  return __builtin_bit_cast(float, (u32)u << 16);
}

// fast transcendentals on the critical path: v_exp_f32 (2^x) + v_rcp_f32, ~1ulp
__device__ __forceinline__ float fexp2(float x) {
  float r; asm("v_exp_f32 %0, %1" : "=v"(r) : "v"(x)); return r;
}
__device__ __forceinline__ float frcp(float x) {
  float r; asm("v_rcp_f32 %0, %1" : "=v"(r) : "v"(x)); return r;
}
__device__ __forceinline__ float sigm(float x) {
  return frcp(1.f + fexp2(-1.44269504f * x));
}
__device__ __forceinline__ float ftanh(float x) {
  float xc = fminf(fmaxf(x, -15.f), 15.f);
  float e = fexp2(2.88539008f * xc);
  return (e - 1.f) * frcp(e + 1.f);
}

// system-scope (MALL-coherent) relaxed ops
__device__ __forceinline__ void sysstore64(void* p, u64 v) {
  __hip_atomic_store((u64*)p, v, __ATOMIC_RELAXED, __HIP_MEMORY_SCOPE_SYSTEM);
}
__device__ __forceinline__ u64 sysload64(const void* p) {
  return __hip_atomic_load((const u64*)p, __ATOMIC_RELAXED, __HIP_MEMORY_SCOPE_SYSTEM);
}

__device__ __forceinline__ void gload_lds16(const u16* gsrc, u16* ldst) {
  __builtin_amdgcn_global_load_lds(
      (__attribute__((address_space(1))) void*)(u16*)gsrc,
      (__attribute__((address_space(3))) void*)ldst, 16, 0, 0);
}

// ---------------- prep: fp32 weights -> bf16 ----------------
__global__ void prep_w_kernel(const float* __restrict__ Wi0, const float* __restrict__ Wh0,
                              const float* __restrict__ Wi1, const float* __restrict__ Wh1,
                              u16* __restrict__ dst) {
  size_t e = ((size_t)blockIdx.x * 256 + threadIdx.x) * 4;   // 16M elements total
  int mat = (int)(e >> 22);
  size_t off = e & ((1ull << 22) - 1);
  const float* src = (mat == 0) ? Wi0 : (mat == 1) ? Wh0 : (mat == 2) ? Wi1 : Wh1;
  float4 v = *(const float4*)(src + off);
  ushort4 o;
  o.x = f2bf(v.x); o.y = f2bf(v.y); o.z = f2bf(v.z); o.w = f2bf(v.w);
  *(ushort4*)(dst + e) = o;
}

__global__ void prep_b_kernel(const float* __restrict__ bi0, const float* __restrict__ bh0,
                              const float* __restrict__ bi1, const float* __restrict__ bh1,
                              float* __restrict__ b0, float* __restrict__ b1) {
  int i = blockIdx.x * 256 + threadIdx.x;   // 4096
  b0[i] = bi0[i] + bh0[i];
  b1[i] = bi1[i] + bh1[i];
}

// ---------------- embedding gather ----------------
__global__ void embed_kernel(const int* __restrict__ x, const float* __restrict__ emb,
                             u16* __restrict__ xe) {
  int m = blockIdx.x;            // m = t*32 + b
  int b = m & 31, t = m >> 5;
  int id = x[b * 512 + t];
  float4 v = ((const float4*)(emb + (size_t)id * 1024))[threadIdx.x];
  ushort4 o;
  o.x = f2bf(v.x); o.y = f2bf(v.y); o.z = f2bf(v.z); o.w = f2bf(v.w);
  *(ushort4*)(xe + (size_t)m * 1024 + threadIdx.x * 4) = o;
}

// ---------------- X0 GEMM -> packed gates Xp: 256x128 tile, 8 waves, counted-vmcnt ----
// Pipeline (T3/T4): raw s_barrier + per-wave vmcnt(6) keeps the next tile's 6 staging
// loads in flight across barriers (no vmcnt(0) drain in steady state). Fragment/swizzle
// addressing identical to the proven 128^2 kernel, only scaled.
__launch_bounds__(512, 1)
__global__ void x0_gemm_kernel(const u16* __restrict__ A, const u16* __restrict__ W,
                               const float* __restrict__ bias, u16* __restrict__ Xp) {
  extern __shared__ u16 lds[];                 // ldsA[2][16384] ++ ldsB[2][8192] = 96KB
  u16* ldsA = lds;
  u16* ldsB = lds + 32768;

  const int tid = threadIdx.x, l = tid & 63, w = tid >> 6;   // 8 waves
  const int n0 = blockIdx.x * 128, m0 = blockIdx.y * 256;
  const int wm = w >> 1, wn = w & 1;           // 4M x 2N wave grid; per-wave 64x64 out
  const int row8 = l >> 3, u = l & 7;

  f32x4 acc[4][4];
#pragma unroll
  for (int a1 = 0; a1 < 4; ++a1)
#pragma unroll
    for (int a2 = 0; a2 < 4; ++a2) acc[a1][a2] = (f32x4){0.f, 0.f, 0.f, 0.f};

  // stage one K-tile (64 cols): A 256 rows (4 calls/wave), B 128 rows (2 calls/wave)
  auto stage = [&](int buf, int kt) {
    const int k0 = kt * 64;
#pragma unroll
    for (int q = 0; q < 4; ++q) {
      const int ld = w * 4 + q;                // 0..31 -> rows 0..255
      const int row = ld * 8 + row8;
      const int sw = (u ^ row8) * 8;           // pre-swizzled source chunk
      gload_lds16(A + (size_t)(m0 + row) * 1024 + k0 + sw, ldsA + buf * 16384 + ld * 512);
    }
#pragma unroll
    for (int q = 0; q < 2; ++q) {
      const int ld = w * 2 + q;                // 0..15 -> rows 0..127
      const int row = ld * 8 + row8;
      const int sw = (u ^ row8) * 8;
      gload_lds16(W + (size_t)(n0 + row) * 1024 + k0 + sw, ldsB + buf * 8192 + ld * 512);
    }
  };

  stage(0, 0);
  stage(1, 1);                                 // 12 loads/wave outstanding

  for (int kt = 0; kt < 16; ++kt) {
    const int cur = kt & 1;
    // wait ONLY for tile kt's 6 loads; tile kt+1's stay in flight across the barrier
    if (kt < 14) asm volatile("s_waitcnt vmcnt(6)" ::: "memory");
    else         asm volatile("s_waitcnt vmcnt(0)" ::: "memory");
    __builtin_amdgcn_s_barrier();              // all waves' tile-kt data in LDS
    __builtin_amdgcn_sched_barrier(0);

    const u16* la = ldsA + cur * 16384;
    const u16* lb = ldsB + cur * 8192;
#pragma unroll
    for (int kk = 0; kk < 2; ++kk) {
      const int c = kk * 4 + (l >> 4);
      const int csw = (c ^ (l & 7)) * 8;       // row&7 == l&7 for all frag rows
      short8 af[4], bf[4];
#pragma unroll
      for (int mi = 0; mi < 4; ++mi) {
        int row = wm * 64 + mi * 16 + (l & 15);
        af[mi] = *(const short8*)(la + row * 64 + csw);
      }
#pragma unroll
      for (int ni = 0; ni < 4; ++ni) {
        int row = wn * 64 + ni * 16 + (l & 15);
        bf[ni] = *(const short8*)(lb + row * 64 + csw);
      }
#pragma unroll
      for (int mi = 0; mi < 4; ++mi)
#pragma unroll
        for (int ni = 0; ni < 4; ++ni)
          acc[mi][ni] = MFMA_BF16(af[mi], bf[ni], acc[mi][ni]);
    }

    if (kt < 14) {
      __builtin_amdgcn_s_barrier();            // all waves done READING buf[cur]
      __builtin_amdgcn_sched_barrier(0);
      stage(cur, kt + 2);                      // overwrite with tile kt+2
    }
  }

  // epilogue: packed write Xp[t][blkid][b][j][g]
#pragma unroll
  for (int ni = 0; ni < 4; ++ni) {
    int col = n0 + wn * 64 + ni * 16 + (l & 15);
    int g = col >> 10, blkid = (col & 1023) >> 2, j = col & 3;
    float bv = bias[col];
#pragma unroll
    for (int mi = 0; mi < 4; ++mi) {
#pragma unroll
      for (int r = 0; r < 4; ++r) {
        int row = m0 + wm * 64 + mi * 16 + (l >> 4) * 4 + r;
        int t = row >> 5, b = row & 31;
        Xp[(size_t)t * 131072 + blkid * 512 + b * 16 + j * 4 + g] =
            f2bf(acc[mi][ni][r] + bv);
      }
    }
  }
}

// ---------------- persistent recurrent kernel (R8/R11 structure, proven) ----------------
// 256 blocks (1/CU), 256 threads (4 waves). Iter i = layer0(t=i) + layer1(t=i-1).
__launch_bounds__(256, 1)
__global__ void lstm_kernel(const u16* __restrict__ wbf, const float* __restrict__ b1v,
                            const u16* __restrict__ Xp, u16* __restrict__ hinit,
                            float* __restrict__ h1f, u32* __restrict__ flagsD) {
  extern __shared__ char smem[];
  u16* wlds = (u16*)smem;                          // 3 * 16384 u16 = 98304 B
  float* gates0 = (float*)(smem + 98304);          // [32][16]  Wh0.h0
  float* part1  = (float*)(smem + 98304 + 2048);   // [32][16]  Wi1.h0
  float* wh1p   = (float*)(smem + 98304 + 4096);   // [32][16]  Wh1.h1

  const int tid = threadIdx.x;
  const int l = tid & 63, w = tid >> 6;
  const int blk = blockIdx.x;
  const int hbase = blk * 4;
  u16* Xw = (u16*)Xp;                              // slot writes into consumed gate slices

  // ---- fill weight LDS in MFMA fragment order
  for (int m = 0; m < 3; ++m) {
    const u16* Wm = wbf + (size_t)(m + 1) * (4096 * 1024);   // 1=Wh0, 2=Wi1, 3=Wh1
    for (int s = tid; s < 2048; s += 256) {
      int kk = s >> 6, ll = s & 63;
      int nl = ll & 15, hi = ll >> 4;
      int gr = (nl >> 2) * 1024 + hbase + (nl & 3);
      short8 v = *(const short8*)(Wm + (size_t)gr * 1024 + kk * 32 + hi * 8);
      *(short8*)(wlds + m * 16384 + kk * 512 + ll * 8) = v;
    }
  }
  __syncthreads();

  float cst = 0.f;                                 // threads 0..127: c0; 128..255: c1
  const int at = tid & 127, ab = at >> 2, aj = at & 3;
  const int mt = w & 1;

  float b1i = 0.f, b1fv = 0.f, b1g = 0.f, b1o = 0.f;
  if (tid >= 128) {
    b1i  = b1v[hbase + aj];
    b1fv = b1v[1024 + hbase + aj];
    b1g  = b1v[2048 + hbase + aj];
    b1o  = b1v[3072 + hbase + aj];
  }

  // gate chunk for step 0 (8B bypass; holds gates g=0..3 for this thread's (ab,aj))
  u64 gchunk = 0;
  if (tid < 128)
    gchunk = sysload64(Xp + blk * 512 + ab * 16 + aj * 4);

  const u32* fquad = flagsD + l * 4;               // wave-0 poll: 4 flags per lane

  for (int i = 0; i <= 512; ++i) {
    const u16* slot_r = (i == 0) ? hinit
                      : (i == 1) ? hinit + 65536
                                 : Xp + (size_t)(i - 2) * 131072;
    u16* slot_w = (i == 0) ? hinit + 65536
                           : Xw + (size_t)(i - 1) * 131072;

    asm volatile("" ::: "memory");   // pin loads below the previous barrier

    // ---- preload ALL h fragments: 32 x 16B NORMAL cached loads (L2-amplified broadcast)
    const u16* abase = slot_r + (w < 2 ? 0 : 32768)
                     + (mt * 16 + (l & 15)) * 1024 + ((l >> 4) * 8);
    short8 ar[32];
#pragma unroll
    for (int kk = 0; kk < 32; ++kk)
      ar[kk] = *(const short8*)(abase + kk * 32);

    if (w < 2) {   // waves 0,1: Wh0.h0 and Wi1.h0 (two independent chains each)
      f32x4 a0a = {0,0,0,0}, a0b = {0,0,0,0}, a1a = {0,0,0,0}, a1b = {0,0,0,0};
#pragma unroll
      for (int kk = 0; kk < 16; ++kk) {
        a0a = MFMA_BF16(ar[2 * kk],     *(const short8*)(wlds + (2 * kk) * 512 + l * 8), a0a);
        a1a = MFMA_BF16(ar[2 * kk],     *(const short8*)(wlds + 16384 + (2 * kk) * 512 + l * 8), a1a);
        a0b = MFMA_BF16(ar[2 * kk + 1], *(const short8*)(wlds + (2 * kk + 1) * 512 + l * 8), a0b);
        a1b = MFMA_BF16(ar[2 * kk + 1], *(const short8*)(wlds + 16384 + (2 * kk + 1) * 512 + l * 8), a1b);
      }
#pragma unroll
      for (int r = 0; r < 4; ++r) {
        int row = mt * 16 + (l >> 4) * 4 + r, col = l & 15;
        gates0[row * 16 + col] = a0a[r] + a0b[r];
        part1[row * 16 + col]  = a1a[r] + a1b[r];
      }
    } else {       // waves 2,3: Wh1.h1
      f32x4 a0a = {0,0,0,0}, a0b = {0,0,0,0};
#pragma unroll
      for (int kk = 0; kk < 16; ++kk) {
        a0a = MFMA_BF16(ar[2 * kk],     *(const short8*)(wlds + 2 * 16384 + (2 * kk) * 512 + l * 8), a0a);
        a0b = MFMA_BF16(ar[2 * kk + 1], *(const short8*)(wlds + 2 * 16384 + (2 * kk + 1) * 512 + l * 8), a0b);
      }
#pragma unroll
      for (int r = 0; r < 4; ++r) {
        int row = mt * 16 + (l >> 4) * 4 + r, col = l & 15;
        wh1p[row * 16 + col] = a0a[r] + a0b[r];
      }
    }
    __syncthreads();

    // ---- activations + h slot store (packed 8B system store per 4 dims)
    if (tid < 128) {
      if (i < 512) {
        float gi = gates0[ab * 16 + aj]      + bf2f((u16)(gchunk));
        float gf = gates0[ab * 16 + 4 + aj]  + bf2f((u16)(gchunk >> 16));
        float gg = gates0[ab * 16 + 8 + aj]  + bf2f((u16)(gchunk >> 32));
        float go = gates0[ab * 16 + 12 + aj] + bf2f((u16)(gchunk >> 48));
        cst = sigm(gf) * cst + sigm(gi) * ftanh(gg);
        float h = sigm(go) * ftanh(cst);
        u32 hv = (u32)f2bf(h);
        u32 p1 = (u32)__shfl_xor((int)hv, 1);
        u32 lo = (aj & 1) ? ((p1 & 0xffff) | (hv << 16)) : ((hv & 0xffff) | (p1 << 16));
        u32 p2 = (u32)__shfl_xor((int)lo, 2);
        if (aj == 0)
          sysstore64(slot_w + ab * 1024 + hbase, (u64)lo | ((u64)p2 << 32));
      }
    } else {
      if (i >= 1) {
        float gi = part1[ab * 16 + aj]      + wh1p[ab * 16 + aj]      + b1i;
        float gf = part1[ab * 16 + 4 + aj]  + wh1p[ab * 16 + 4 + aj]  + b1fv;
        float gg = part1[ab * 16 + 8 + aj]  + wh1p[ab * 16 + 8 + aj]  + b1g;
        float go = part1[ab * 16 + 12 + aj] + wh1p[ab * 16 + 12 + aj] + b1o;
        cst = sigm(gf) * cst + sigm(gi) * ftanh(gg);
        float h = sigm(go) * ftanh(cst);
        u32 hv = (u32)f2bf(h);
        u32 p1 = (u32)__shfl_xor((int)hv, 1);
        u32 lo = (aj & 1) ? ((p1 & 0xffff) | (hv << 16)) : ((hv & 0xffff) | (p1 << 16));
        u32 p2 = (u32)__shfl_xor((int)lo, 2);
        if (aj == 0)
          sysstore64(slot_w + 32768 + ab * 1024 + hbase, (u64)lo | ((u64)p2 << 32));
        if (i == 512) h1f[ab * 1024 + hbase + aj] = h;
      }
    }

    if (i == 512) break;                 // done; no final barrier needed

    // ---- dense-flag barrier: post, prefetch gates, wave-0 poll
    __syncthreads();                     // all h system-stores drained (vmcnt 0, all waves)
    const u32 target = (u32)(i + 1);
    if (tid == 0)
      __hip_atomic_store(&flagsD[blk], target, __ATOMIC_RELAXED, __HIP_MEMORY_SCOPE_SYSTEM);

    // prefetch next step's gate chunk under the barrier wait
    if (tid < 128 && i + 1 < 512)
      gchunk = sysload64(Xp + (size_t)(i + 1) * 131072 + blk * 512 + ab * 16 + aj * 4);

    if (w == 0) {                        // 64 lanes x 4 flags = all 256, one 16B load/lane
      while (true) {
        i32x4 v;
        asm volatile("global_load_dwordx4 %0, %1, off sc0 sc1"
                     : "=&v"(v) : "v"(fquad));
        asm volatile("s_waitcnt vmcnt(0)" ::: "memory");
        u32 m01 = min((u32)v.x, (u32)v.y);
        u32 m23 = min((u32)v.z, (u32)v.w);
        if (__all(min(m01, m23) >= target)) break;
      }
    }
    __syncthreads();                     // whole block proceeds once wave 0 confirms
  }
}

// ---------------- final FC: fcw read exactly once; h1 staged in LDS ----------------
__global__ void __launch_bounds__(512) fc_kernel(const float* __restrict__ h1f,
                                                 const float* __restrict__ fcw,
                                                 const float* __restrict__ fcb,
                                                 float* __restrict__ out) {
  extern __shared__ float hls[];                  // [32][1024] fp32 = 128KB
  for (int s = threadIdx.x; s < 8192; s += 512)
    ((float4*)hls)[s] = ((const float4*)h1f)[s];
  __syncthreads();
  const int w = threadIdx.x >> 6, l = threadIdx.x & 63;
  const int vbase = blockIdx.x * 128 + w * 16;    // grid 250 x 8 waves x 16 v = 32000
  for (int vi = 0; vi < 16; ++vi) {
    const int v = vbase + vi;
    const float4* wr = (const float4*)(fcw + (size_t)v * 1024);
    float4 f0 = wr[l], f1 = wr[64 + l], f2 = wr[128 + l], f3 = wr[192 + l];
    float bias = fcb[v];
    for (int b = 0; b < 32; ++b) {
      const float4* hb = (const float4*)(hls + b * 1024);
      float4 h0 = hb[l], h1 = hb[64 + l], h2 = hb[128 + l], h3 = hb[192 + l];
      float s = f0.x*h0.x + f0.y*h0.y + f0.z*h0.z + f0.w*h0.w
              + f1.x*h1.x + f1.y*h1.y + f1.z*h1.z + f1.w*h1.w
              + f2.x*h2.x + f2.y*h2.y + f2.z*h2.z + f2.w*h2.w
              + f3.x*h3.x + f3.y*h3.y + f3.z*h3.z + f3.w*h3.w;
      s += __shfl_xor(s, 1);  s += __shfl_xor(s, 2);  s += __shfl_xor(s, 4);
      s += __shfl_xor(s, 8);  s += __shfl_xor(s, 16); s += __shfl_xor(s, 32);
      if (l == 0) out[(size_t)b * 32000 + v] = s + bias;
    }
  }
}

// ---------------- host launch ----------------
extern "C" void kernel_launch(void* const* d_in, const int* in_sizes, int n_in,
                              void* d_out, int out_size, void* d_ws, size_t ws_size,
                              hipStream_t stream) {
  const int*   x   = (const int*)d_in[0];
  const float* emb = (const float*)d_in[1];
  const float* Wi0 = (const float*)d_in[2];
  const float* bi0 = (const float*)d_in[3];
  const float* Wh0 = (const float*)d_in[4];
  const float* bh0 = (const float*)d_in[5];
  const float* Wi1 = (const float*)d_in[6];
  const float* bi1 = (const float*)d_in[7];
  const float* Wh1 = (const float*)d_in[8];
  const float* bh1 = (const float*)d_in[9];
  const float* fcw = (const float*)d_in[10];
  const float* fcb = (const float*)d_in[11];
  float* out = (float*)d_out;
  char* ws = (char*)d_ws;

  if (ws_size < WS_NEED) return;

  u16*   wbf = (u16*)(ws + OFF_W);
  float* b0v = (float*)(ws + OFF_B0);
  float* b1v = (float*)(ws + OFF_B1);
  u16*   hin = (u16*)(ws + OFF_H0);
  float* h1f = (float*)(ws + OFF_H1F);
  u16*   xe  = (u16*)(ws + OFF_XE);
  u16*   Xp  = (u16*)(ws + OFF_X0);
  u32*   flg = (u32*)(ws + OFF_FLG);

  // zero init slots + h1f every call (replays must be identical)
  hipMemsetAsync(ws + OFF_H0, 0, OFF_XE - OFF_H0, stream);

  prep_w_kernel<<<16384, 256, 0, stream>>>(Wi0, Wh0, Wi1, Wh1, wbf);
  prep_b_kernel<<<16, 256, 0, stream>>>(bi0, bh0, bi1, bh1, b0v, b1v);
  embed_kernel<<<16384, 256, 0, stream>>>(x, emb, xe);

  hipFuncSetAttribute((const void*)x0_gemm_kernel,
                      hipFuncAttributeMaxDynamicSharedMemorySize, 98304);
  x0_gemm_kernel<<<dim3(32, 64), 512, 98304, stream>>>(xe, wbf, b0v, Xp);

  // xe tail is dead now -> dense barrier flags (zeroed per call)
  hipMemsetAsync(ws + OFF_FLG, 0, 4096, stream);

  hipFuncSetAttribute((const void*)lstm_kernel,
                      hipFuncAttributeMaxDynamicSharedMemorySize, 104448);
  lstm_kernel<<<256, 256, 104448, stream>>>(wbf, b1v, Xp, hin, h1f, flg);

  hipFuncSetAttribute((const void*)fc_kernel,
                      hipFuncAttributeMaxDynamicSharedMemorySize, 131072);
  fc_kernel<<<250, 512, 131072, stream>>>(h1f, fcw, fcb, out);
}